// Round 12
// baseline (273.840 us; speedup 1.0000x reference)
//
#include <hip/hip_runtime.h>
#include <math.h>

// VIN forward on MI355X.
// Sizes: N=128, H=W=64, CH_I=2, CH_H=150, CH_Q=10, N_ACT=8, VInum=36.
//
// R11 -> R12 changes:
//  * pk fp32 reverted for good (R6+R11: halves VALU issue, never improves
//    wall -> v_pk_fma_f32 is effectively half-rate/FLOP here). K-loop is
//    R10's proven scalar form.
//  * Engage all 256 CUs: 256 WGs (image, half), TRAPEZOID chunking: each WG
//    carries an 8-row halo margin that shrinks 1 row/iter; pairs exchange
//    halo rows only when margin hits 0 -> 4 exchanges/kernel (R8 synced every
//    iter = 35x). Exchange: plain stores -> barrier -> t0 release-flag +
//    relaxed spin (s_sleep) + acquire -> agent-scope relaxed payload loads.
//  * Co-residency (spin safety) via hipLaunchCooperativeKernel; LDS ~102KB
//    forces exactly 1 WG/CU (fixes R8's silent 2-WG packing).
//  * Host checks ws_size; falls back to the 128-WG R10 kernel if the 1MB
//    mailbox doesn't fit (deterministic -> graph-capture safe).

#define XROW 69
#define VROW 67
#define VSTR (66 * VROW)          // 4422 floats per v buffer
#define PAY_FLOATS (256 * 2 * 512)  // 262144 floats = 1 MB payload
#define WS_NEED_BYTES ((PAY_FLOATS + 256) * 4)

__global__ void init_flags(int* flags) { flags[threadIdx.x] = 0; }

// ---------------------------------------------------------------------------
// Shared prologue macro (class-stencil r computation, R10 form)
// ---------------------------------------------------------------------------
#define VIN_PROLOGUE(NTHR)                                                    \
    for (int i = t; i < 68 * XROW; i += NTHR) { xs0[i] = 0.f; xs1[i] = 0.f; } \
    for (int i = t; i < 66 * VROW; i += NTHR) rs[i] = 0.f;                    \
    for (int i = t; i < 2 * VSTR; i += NTHR) vpool[i] = 0.f;                  \
    if (t < 450) Pp[t] = 0.f;                                                 \
    if (t < 90) swv[t] = w_sw[(t / 10) * 20 + 10 + (t % 10)];                 \
    __syncthreads();                                                          \
    {                                                                         \
        const float* xb = x + (size_t)b * 64 * 64 * 2;                        \
        const float4* xp = (const float4*)(xb + (rowP * 64 + cbP) * 2);       \
        _Pragma("unroll")                                                     \
        for (int g = 0; g < 4; ++g) {                                         \
            float4 v4 = xp[g];                                                \
            int px = cbP + g * 2;                                             \
            xs0[(rowP + 2) * XROW + px + 2] = v4.x;                           \
            xs1[(rowP + 2) * XROW + px + 2] = v4.y;                           \
            xs0[(rowP + 2) * XROW + px + 3] = v4.z;                           \
            xs1[(rowP + 2) * XROW + px + 3] = v4.w;                           \
        }                                                                     \
    }                                                                         \
    for (int w = t; w < 1620; w += NTHR) {                                    \
        int entry = w / 10, ch = w - entry * 10;                              \
        int d = entry / 18, rem = entry % 18;                                 \
        int uu = rem >> 1, ci = rem & 1;                                      \
        int c0 = ch * 15;                                                     \
        const float* wr = w_r + d * 150;                                      \
        const float* wp = w0 + (uu * 2 + ci) * 150;                           \
        float s = 0.f;                                                        \
        for (int c = c0; c < c0 + 15; ++c) s += wr[c] * wp[c];                \
        wtA[w] = s;                                                           \
    }                                                                         \
    if (t < 90) {                                                             \
        int d = t / 10, ch = t - d * 10, c0 = ch * 15;                        \
        float s = 0.f;                                                        \
        for (int c = c0; c < c0 + 15; ++c) s += w_r[d * 150 + c] * b0[c];     \
        Bt[t] = s;                                                            \
    }                                                                         \
    __syncthreads();                                                          \
    if (t < 162) {                                                            \
        float s = 0.f;                                                        \
        _Pragma("unroll")                                                     \
        for (int i = 0; i < 10; ++i) s += wtA[t * 10 + i];                    \
        int d = t / 18, rem = t % 18;                                         \
        int uu = rem >> 1, ci = rem & 1;                                      \
        int dy = d / 3 - 1, dx = d % 3 - 1;                                   \
        int uy = uu / 3 - 1, ux = uu % 3 - 1;                                 \
        int eidx = (dy + uy + 2) * 5 + (dx + ux + 2);                         \
        Pp[d * 50 + eidx * 2 + ci] = s;                                       \
    } else if (t >= 256 && t < 265) {                                         \
        int d = t - 256;                                                      \
        float s = 0.f;                                                        \
        _Pragma("unroll")                                                     \
        for (int i = 0; i < 10; ++i) s += Bt[d * 10 + i];                     \
        Bv[d] = s;                                                            \
    }                                                                         \
    __syncthreads();                                                          \
    if (t < 459) {                                                            \
        int cls = t / 51, j = t - cls * 51;                                   \
        int cy = cls / 3, cx = cls % 3;                                       \
        float s = 0.f;                                                        \
        _Pragma("unroll")                                                     \
        for (int d = 0; d < 9; ++d) {                                         \
            int dy = d / 3 - 1, dx = d % 3 - 1;                               \
            bool ok = (cy == 0 || (cy == 1 ? dy >= 0 : dy <= 0)) &&           \
                      (cx == 0 || (cx == 1 ? dx >= 0 : dx <= 0));             \
            if (ok) s += (j < 50) ? Pp[d * 50 + j] : Bv[d];                   \
        }                                                                     \
        W5c[t] = s;                                                           \
    }                                                                         \
    __syncthreads();                                                          \
    {                                                                         \
        int cy = (rowP == 0) ? 1 : (rowP == 63) ? 2 : 0;                      \
        _Pragma("unroll")                                                     \
        for (int p = 0; p < 8; ++p) {                                         \
            int xx = cbP + p;                                                 \
            int cx = (xx == 0) ? 1 : (xx == 63) ? 2 : 0;                      \
            const float* Wp = &W5c[(cy * 3 + cx) * 51];                       \
            float acc = Wp[50];                                               \
            _Pragma("unroll")                                                 \
            for (int e = 0; e < 25; ++e) {                                    \
                int xi = (rowP + e / 5) * XROW + (xx + e % 5);                \
                acc = fmaf(xs0[xi], Wp[e * 2], acc);                          \
                acc = fmaf(xs1[xi], Wp[e * 2 + 1], acc);                      \
            }                                                                 \
            rs[(rowP + 1) * VROW + (xx + 1)] = acc;                           \
        }                                                                     \
    }                                                                         \
    __syncthreads();

// ---------------------------------------------------------------------------
// Split kernel: 256 WGs = (image, half), trapezoid margin + 4 exchanges
// ---------------------------------------------------------------------------
__global__ void
__attribute__((amdgpu_flat_work_group_size(512, 512)))
__attribute__((amdgpu_waves_per_eu(2, 2)))
vin_split(const float* __restrict__ x,
          const int* __restrict__ S1,
          const int* __restrict__ S2,
          const int* __restrict__ VInum,
          const float* __restrict__ w0,
          const float* __restrict__ b0,
          const float* __restrict__ w_r,
          const float* __restrict__ w_q,
          const float* __restrict__ w_sw,
          const float* __restrict__ w_sw2,
          const float* __restrict__ w_dense,
          float* __restrict__ wsf,
          float* __restrict__ out) {
    const int wg = blockIdx.x;
    const int b = wg >> 1, h = wg & 1;
    const int partner = wg ^ 1;
    const int t = threadIdx.x;
    int* flags = (int*)(wsf + PAY_FLOATS);

    __shared__ float xs0[68 * XROW];
    __shared__ float xs1[68 * XROW];
    __shared__ float rs[66 * VROW];
    __shared__ float vpool[2 * VSTR];
    __shared__ float wtA[1620];
    __shared__ float Pp[450];
    __shared__ float Bt[90];
    __shared__ float Bv[9];
    __shared__ float W5c[459];
    __shared__ float swv[90];
    __shared__ float qsel[10];

    const int rowP = t >> 3;         // prologue mapping: 8 px/thread
    const int cbP  = (t & 7) << 3;

    VIN_PROLOGUE(512)

    const int K = VInum[0];
    const int row = t >> 3;          // K-loop mapping (same): 0..63
    const int cb  = (t & 7) << 3;

    // ---- Rsw precompute + first step (w_q): full image (rs fully valid) ----
    float Rsw[8][10];
    {
        float rwin[3][10];
        #pragma unroll
        for (int i = 0; i < 3; ++i) {
            const float* rp = &rs[(row + i) * VROW + cb];
            #pragma unroll
            for (int j = 0; j < 10; ++j) rwin[i][j] = rp[j];
        }
        float vmax[8];
        #pragma unroll
        for (int a = 0; a < 10; ++a) {
            #pragma unroll
            for (int p = 0; p < 8; ++p) {
                float accR = 0.f, accQ = 0.f;
                #pragma unroll
                for (int d = 0; d < 9; ++d) {
                    float rv = rwin[d / 3][p + d % 3];
                    accR = fmaf(w_sw[d * 20 + a], rv, accR);
                    accQ = fmaf(w_q[d * 20 + a],  rv, accQ);
                }
                Rsw[p][a] = accR;
                vmax[p] = (a == 0) ? accQ : fmaxf(vmax[p], accQ);
            }
        }
        #pragma unroll
        for (int p = 0; p < 8; ++p)
            vpool[0 * VSTR + (row + 1) * VROW + (cb + p + 1)] = vmax[p];
    }
    __syncthreads();

    // ---- K-1 VI steps with shrinking 8-row margin; exchange at m==0 ----
    int cur = 0, m = 8, chunk = 0;
    for (int it = 0; it < K - 1; ++it) {
        int nxt = cur ^ 1;
        bool active = h ? (row >= 33 - m) : (row < 31 + m);
        if (active) {
            const float* vb = &vpool[cur * VSTR + row * VROW + cb];
            float vwin[3][10];
            #pragma unroll
            for (int i = 0; i < 3; ++i)
                #pragma unroll
                for (int j = 0; j < 10; ++j) vwin[i][j] = vb[i * VROW + j];
            float vmax[8];
            #pragma unroll
            for (int a = 0; a < 10; ++a) {
                #pragma unroll
                for (int p = 0; p < 8; ++p) {
                    float acc = Rsw[p][a];
                    #pragma unroll
                    for (int d = 0; d < 9; ++d)
                        acc = fmaf(swv[d * 10 + a], vwin[d / 3][p + d % 3], acc);
                    vmax[p] = (a == 0) ? acc : fmaxf(vmax[p], acc);
                }
            }
            #pragma unroll
            for (int p = 0; p < 8; ++p)
                vpool[nxt * VSTR + (row + 1) * VROW + (cb + p + 1)] = vmax[p];
        }
        cur = nxt;
        m -= 1;
        __syncthreads();

        if (m == 0) {                 // halo exchange (uniform; 4x for K=36)
            ++chunk;
            int par = chunk & 1;
            if (t < 128) {            // publish own 8 boundary rows (2 KB)
                int lr2 = t >> 4, col = (t & 15) << 2;
                int srow = (h ? 32 : 24) + lr2;
                const float* sp = &vpool[cur * VSTR + (srow + 1) * VROW + col + 1];
                float* dp = wsf + ((size_t)(wg * 2 + par)) * 512 + t * 4;
                dp[0] = sp[0]; dp[1] = sp[1]; dp[2] = sp[2]; dp[3] = sp[3];
            }
            __syncthreads();
            if (t == 0) {
                __threadfence();
                __hip_atomic_store(&flags[wg], chunk, __ATOMIC_RELEASE,
                                   __HIP_MEMORY_SCOPE_AGENT);
                while (__hip_atomic_load(&flags[partner], __ATOMIC_RELAXED,
                                         __HIP_MEMORY_SCOPE_AGENT) < chunk)
                    __builtin_amdgcn_s_sleep(2);
                (void)__hip_atomic_load(&flags[partner], __ATOMIC_ACQUIRE,
                                        __HIP_MEMORY_SCOPE_AGENT);
            }
            __syncthreads();
            if (t < 128) {            // fetch partner rows (bypass stale L1)
                int lr2 = t >> 4, col = (t & 15) << 2;
                int rrow = (h ? 24 : 32) + lr2;
                const float* sp = wsf + ((size_t)(partner * 2 + par)) * 512 + t * 4;
                float v0 = __hip_atomic_load(&sp[0], __ATOMIC_RELAXED, __HIP_MEMORY_SCOPE_AGENT);
                float v1 = __hip_atomic_load(&sp[1], __ATOMIC_RELAXED, __HIP_MEMORY_SCOPE_AGENT);
                float v2 = __hip_atomic_load(&sp[2], __ATOMIC_RELAXED, __HIP_MEMORY_SCOPE_AGENT);
                float v3 = __hip_atomic_load(&sp[3], __ATOMIC_RELAXED, __HIP_MEMORY_SCOPE_AGENT);
                float* dp = &vpool[cur * VSTR + (rrow + 1) * VROW + col + 1];
                dp[0] = v0; dp[1] = v1; dp[2] = v2; dp[3] = v3;
            }
            m = 8;
            __syncthreads();
        }
    }

    // ---- final step with w_sw2 on own half only ----
    const int s1 = S1[b], s2 = S2[b];
    const bool owner = ((s1 >> 5) == h);
    if ((row >> 5) == h) {
        float rwin[3][10], vwin[3][10];
        #pragma unroll
        for (int i = 0; i < 3; ++i) {
            const float* rp = &rs[(row + i) * VROW + cb];
            const float* vb = &vpool[cur * VSTR + (row + i) * VROW + cb];
            #pragma unroll
            for (int j = 0; j < 10; ++j) { rwin[i][j] = rp[j]; vwin[i][j] = vb[j]; }
        }
        float qv[8][10];
        #pragma unroll
        for (int a = 0; a < 10; ++a) {
            #pragma unroll
            for (int p = 0; p < 8; ++p) {
                float acc = 0.f;
                #pragma unroll
                for (int d = 0; d < 9; ++d) {
                    acc = fmaf(w_sw2[d * 20 + a],      rwin[d / 3][p + d % 3], acc);
                    acc = fmaf(w_sw2[d * 20 + 10 + a], vwin[d / 3][p + d % 3], acc);
                }
                qv[p][a] = acc;
            }
        }
        float4* qp4 = (float4*)(out + 2048 + ((size_t)((b * 64 + row) * 64 + cb)) * 10);
        #pragma unroll
        for (int g = 0; g < 20; ++g)
            qp4[g] = make_float4(qv[(g * 4) / 10][(g * 4) % 10],
                                 qv[(g * 4 + 1) / 10][(g * 4 + 1) % 10],
                                 qv[(g * 4 + 2) / 10][(g * 4 + 2) % 10],
                                 qv[(g * 4 + 3) / 10][(g * 4 + 3) % 10]);
        if (owner && row == s1) {
            #pragma unroll
            for (int p = 0; p < 8; ++p)
                if (s2 == cb + p) {
                    #pragma unroll
                    for (int a = 0; a < 10; ++a) qsel[a] = qv[p][a];
                }
        }
    }
    __syncthreads();

    if (owner && t == 0) {
        float logits[8];
        float mx = -1e30f;
        #pragma unroll
        for (int j = 0; j < 8; ++j) {
            float s = 0.f;
            #pragma unroll
            for (int a = 0; a < 10; ++a) s += qsel[a] * w_dense[a * 8 + j];
            logits[j] = s;
            mx = fmaxf(mx, s);
        }
        float sum = 0.f;
        float e[8];
        #pragma unroll
        for (int j = 0; j < 8; ++j) { e[j] = expf(logits[j] - mx); sum += e[j]; }
        float inv = 1.f / sum;
        #pragma unroll
        for (int j = 0; j < 8; ++j) {
            out[b * 8 + j] = logits[j];
            out[1024 + b * 8 + j] = e[j] * inv;
        }
    }
    if (owner && t < 10) out[5244928 + b * 10 + t] = qsel[t];
}

// ---------------------------------------------------------------------------
// Fallback: R10's 128-WG monolithic kernel (used if ws_size too small)
// ---------------------------------------------------------------------------
__global__ void
__attribute__((amdgpu_flat_work_group_size(512, 512)))
__attribute__((amdgpu_waves_per_eu(2, 2)))
vin_full(const float* __restrict__ x,
         const int* __restrict__ S1,
         const int* __restrict__ S2,
         const int* __restrict__ VInum,
         const float* __restrict__ w0,
         const float* __restrict__ b0,
         const float* __restrict__ w_r,
         const float* __restrict__ w_q,
         const float* __restrict__ w_sw,
         const float* __restrict__ w_sw2,
         const float* __restrict__ w_dense,
         float* __restrict__ out) {
    const int b = blockIdx.x;
    const int t = threadIdx.x;

    __shared__ float xs0[68 * XROW];
    __shared__ float xs1[68 * XROW];
    __shared__ float rs[66 * VROW];
    __shared__ float vpool[2 * VSTR];
    __shared__ float wtA[1620];
    __shared__ float Pp[450];
    __shared__ float Bt[90];
    __shared__ float Bv[9];
    __shared__ float W5c[459];
    __shared__ float swv[90];
    __shared__ float qsel[10];

    const int rowP = t >> 3;
    const int cbP  = (t & 7) << 3;

    VIN_PROLOGUE(512)

    const int K = VInum[0];
    const int row = t >> 3;
    const int cb  = (t & 7) << 3;

    float Rsw[8][10];
    {
        float rwin[3][10];
        #pragma unroll
        for (int i = 0; i < 3; ++i) {
            const float* rp = &rs[(row + i) * VROW + cb];
            #pragma unroll
            for (int j = 0; j < 10; ++j) rwin[i][j] = rp[j];
        }
        float vmax[8];
        #pragma unroll
        for (int a = 0; a < 10; ++a) {
            #pragma unroll
            for (int p = 0; p < 8; ++p) {
                float accR = 0.f, accQ = 0.f;
                #pragma unroll
                for (int d = 0; d < 9; ++d) {
                    float rv = rwin[d / 3][p + d % 3];
                    accR = fmaf(w_sw[d * 20 + a], rv, accR);
                    accQ = fmaf(w_q[d * 20 + a],  rv, accQ);
                }
                Rsw[p][a] = accR;
                vmax[p] = (a == 0) ? accQ : fmaxf(vmax[p], accQ);
            }
        }
        #pragma unroll
        for (int p = 0; p < 8; ++p)
            vpool[0 * VSTR + (row + 1) * VROW + (cb + p + 1)] = vmax[p];
    }
    __syncthreads();

    int cur = 0;
    for (int it = 0; it < K - 1; ++it) {
        const float* vb = &vpool[cur * VSTR + row * VROW + cb];
        float vwin[3][10];
        #pragma unroll
        for (int i = 0; i < 3; ++i)
            #pragma unroll
            for (int j = 0; j < 10; ++j) vwin[i][j] = vb[i * VROW + j];
        int nxt = cur ^ 1;
        float vmax[8];
        #pragma unroll
        for (int a = 0; a < 10; ++a) {
            #pragma unroll
            for (int p = 0; p < 8; ++p) {
                float acc = Rsw[p][a];
                #pragma unroll
                for (int d = 0; d < 9; ++d)
                    acc = fmaf(swv[d * 10 + a], vwin[d / 3][p + d % 3], acc);
                vmax[p] = (a == 0) ? acc : fmaxf(vmax[p], acc);
            }
        }
        #pragma unroll
        for (int p = 0; p < 8; ++p)
            vpool[nxt * VSTR + (row + 1) * VROW + (cb + p + 1)] = vmax[p];
        cur = nxt;
        __syncthreads();
    }

    const int s1 = S1[b], s2 = S2[b];
    {
        float rwin[3][10], vwin[3][10];
        #pragma unroll
        for (int i = 0; i < 3; ++i) {
            const float* rp = &rs[(row + i) * VROW + cb];
            const float* vb = &vpool[cur * VSTR + (row + i) * VROW + cb];
            #pragma unroll
            for (int j = 0; j < 10; ++j) { rwin[i][j] = rp[j]; vwin[i][j] = vb[j]; }
        }
        float qv[8][10];
        #pragma unroll
        for (int a = 0; a < 10; ++a) {
            #pragma unroll
            for (int p = 0; p < 8; ++p) {
                float acc = 0.f;
                #pragma unroll
                for (int d = 0; d < 9; ++d) {
                    acc = fmaf(w_sw2[d * 20 + a],      rwin[d / 3][p + d % 3], acc);
                    acc = fmaf(w_sw2[d * 20 + 10 + a], vwin[d / 3][p + d % 3], acc);
                }
                qv[p][a] = acc;
            }
        }
        float4* qp4 = (float4*)(out + 2048 + ((size_t)((b * 64 + row) * 64 + cb)) * 10);
        #pragma unroll
        for (int g = 0; g < 20; ++g)
            qp4[g] = make_float4(qv[(g * 4) / 10][(g * 4) % 10],
                                 qv[(g * 4 + 1) / 10][(g * 4 + 1) % 10],
                                 qv[(g * 4 + 2) / 10][(g * 4 + 2) % 10],
                                 qv[(g * 4 + 3) / 10][(g * 4 + 3) % 10]);
        if (row == s1) {
            #pragma unroll
            for (int p = 0; p < 8; ++p)
                if (s2 == cb + p) {
                    #pragma unroll
                    for (int a = 0; a < 10; ++a) qsel[a] = qv[p][a];
                }
        }
    }
    __syncthreads();

    if (t == 0) {
        float logits[8];
        float mx = -1e30f;
        #pragma unroll
        for (int j = 0; j < 8; ++j) {
            float s = 0.f;
            #pragma unroll
            for (int a = 0; a < 10; ++a) s += qsel[a] * w_dense[a * 8 + j];
            logits[j] = s;
            mx = fmaxf(mx, s);
        }
        float sum = 0.f;
        float e[8];
        #pragma unroll
        for (int j = 0; j < 8; ++j) { e[j] = expf(logits[j] - mx); sum += e[j]; }
        float inv = 1.f / sum;
        #pragma unroll
        for (int j = 0; j < 8; ++j) {
            out[b * 8 + j] = logits[j];
            out[1024 + b * 8 + j] = e[j] * inv;
        }
    }
    if (t < 10) out[5244928 + b * 10 + t] = qsel[t];
}

extern "C" void kernel_launch(void* const* d_in, const int* in_sizes, int n_in,
                              void* d_out, int out_size, void* d_ws, size_t ws_size,
                              hipStream_t stream) {
    const float* x      = (const float*)d_in[0];
    const int*   S1     = (const int*)d_in[1];
    const int*   S2     = (const int*)d_in[2];
    const int*   VInum  = (const int*)d_in[3];
    const float* w0     = (const float*)d_in[4];
    const float* b0     = (const float*)d_in[5];
    const float* w_r    = (const float*)d_in[6];
    const float* w_q    = (const float*)d_in[7];
    const float* w_sw   = (const float*)d_in[8];
    const float* w_sw2  = (const float*)d_in[9];
    const float* w_dense= (const float*)d_in[10];
    float* out = (float*)d_out;
    float* wsf = (float*)d_ws;

    if (ws_size >= (size_t)WS_NEED_BYTES) {
        init_flags<<<1, 256, 0, stream>>>((int*)(wsf + PAY_FLOATS));
        void* args[] = {(void*)&x, (void*)&S1, (void*)&S2, (void*)&VInum,
                        (void*)&w0, (void*)&b0, (void*)&w_r, (void*)&w_q,
                        (void*)&w_sw, (void*)&w_sw2, (void*)&w_dense,
                        (void*)&wsf, (void*)&out};
        hipLaunchCooperativeKernel((const void*)vin_split, dim3(256), dim3(512),
                                   args, 0, stream);
    } else {
        vin_full<<<128, 512, 0, stream>>>(x, S1, S2, VInum, w0, b0, w_r, w_q,
                                          w_sw, w_sw2, w_dense, out);
    }
}

// Round 13
// 224.007 us; speedup vs baseline: 1.2225x; 1.2225x over previous
//
#include <hip/hip_runtime.h>
#include <math.h>

// VIN forward on MI355X — single fused kernel (128 WGs x 512 thr, 8 px/thread).
// Sizes: N=128, H=W=64, CH_I=2, CH_H=150, CH_Q=10, N_ACT=8, VInum=36.
//
// R12 -> R13 changes:
//  * Split-WG abandoned permanently (R8 + R12: cross-WG per-iter coupling on
//    non-coherent XCD L2s costs more than the 2x CU gain; 4-exchange trapezoid
//    still lost 48us to sync + thin-wave latency exposure).
//  * K-loop weights now read DIRECTLY FROM GLOBAL w_sw instead of LDS:
//    90 loop-invariant wave-uniform addresses -> s_load into SGPRs (scalar
//    pipe + K$), FMA consumes the SGPR operand directly. LDS pipe traffic
//    drops 128 -> 38 instr/thread/iter; VALU unchanged. This removes the
//    ds_read weight stream the allocator kept refolding (R5/R6/R7) without
//    fighting the remat cost model.

#define XROW 69
#define VROW 67
#define VSTR (66 * VROW)          // 4422 floats per v buffer

__global__ void
__attribute__((amdgpu_flat_work_group_size(512, 512)))
__attribute__((amdgpu_waves_per_eu(2, 2)))
vin_kernel(const float* __restrict__ x,
           const int* __restrict__ S1,
           const int* __restrict__ S2,
           const int* __restrict__ VInum,
           const float* __restrict__ w0,
           const float* __restrict__ b0,
           const float* __restrict__ w_r,
           const float* __restrict__ w_q,
           const float* __restrict__ w_sw,
           const float* __restrict__ w_sw2,
           const float* __restrict__ w_dense,
           float* __restrict__ out) {
    const int b = blockIdx.x;
    const int t = threadIdx.x;

    __shared__ float xs0[68 * XROW];     // x ch0, [y+2][x+2], 2-halo of zeros
    __shared__ float xs1[68 * XROW];     // x ch1
    __shared__ float rs[66 * VROW];      // r with 1-halo of zeros
    __shared__ float vpool[2 * VSTR];    // v double buffer, 1-halo of zeros
    __shared__ float wtA[1620];          // P chunk partials: 162 entries x 10
    __shared__ float Pp[450];            // P[d][e5x5][ci], zero-init (162 filled)
    __shared__ float Bt[90];             // bias chunk partials: 9 d x 10
    __shared__ float Bv[9];              // B[d] = w_r[d].b0
    __shared__ float W5c[459];           // 9 classes x (50 weights + bias)
    __shared__ float qsel[10];

    // ---- zero LDS (halos must be 0; Pp must be 0 for invalid combos) ----
    for (int i = t; i < 68 * XROW; i += 512) { xs0[i] = 0.f; xs1[i] = 0.f; }
    for (int i = t; i < 66 * VROW; i += 512) rs[i] = 0.f;
    for (int i = t; i < 2 * VSTR; i += 512) vpool[i] = 0.f;
    if (t < 450) Pp[t] = 0.f;
    __syncthreads();

    const int row = t >> 3;          // 0..63
    const int cb  = (t & 7) << 3;    // 0,8,...,56  (8 px per thread)

    // ---- stage x into split planes (16 contiguous floats = 4x float4) ----
    {
        const float* xb = x + (size_t)b * 64 * 64 * 2;
        const float4* xp = (const float4*)(xb + (row * 64 + cb) * 2);
        #pragma unroll
        for (int g = 0; g < 4; ++g) {
            float4 v4 = xp[g];
            int px = cb + g * 2;
            xs0[(row + 2) * XROW + px + 2] = v4.x;
            xs1[(row + 2) * XROW + px + 2] = v4.y;
            xs0[(row + 2) * XROW + px + 3] = v4.z;
            xs1[(row + 2) * XROW + px + 3] = v4.w;
        }
    }
    // ---- round A: P chunk partials (1620 items) + bias chunks (90) ----
    for (int idx = t; idx < 1620; idx += 512) {
        int entry = idx / 10, ch = idx - entry * 10;
        int d = entry / 18, rem = entry % 18;
        int uu = rem >> 1, ci = rem & 1;
        int c0 = ch * 15;
        const float* wr = w_r + d * 150;
        const float* wp = w0 + (uu * 2 + ci) * 150;
        float s = 0.f;
        for (int c = c0; c < c0 + 15; ++c) s += wr[c] * wp[c];
        wtA[idx] = s;
    }
    if (t < 90) {
        int d = t / 10, ch = t - d * 10, c0 = ch * 15;
        float s = 0.f;
        for (int c = c0; c < c0 + 15; ++c) s += w_r[d * 150 + c] * b0[c];
        Bt[t] = s;
    }
    __syncthreads();
    // ---- round B: reduce P entries (162) and B (9) ----
    if (t < 162) {
        float s = 0.f;
        #pragma unroll
        for (int i = 0; i < 10; ++i) s += wtA[t * 10 + i];
        int d = t / 18, rem = t % 18;
        int uu = rem >> 1, ci = rem & 1;
        int dy = d / 3 - 1, dx = d % 3 - 1;
        int uy = uu / 3 - 1, ux = uu % 3 - 1;
        int eidx = (dy + uy + 2) * 5 + (dx + ux + 2);
        Pp[d * 50 + eidx * 2 + ci] = s;
    } else if (t >= 256 && t < 265) {
        int d = t - 256;
        float s = 0.f;
        #pragma unroll
        for (int i = 0; i < 10; ++i) s += Bt[d * 10 + i];
        Bv[d] = s;
    }
    __syncthreads();
    // ---- round C: class subset-sums W5c[9][51] ----
    if (t < 459) {
        int cls = t / 51, j = t - cls * 51;
        int cy = cls / 3, cx = cls % 3;
        float s = 0.f;
        #pragma unroll
        for (int d = 0; d < 9; ++d) {
            int dy = d / 3 - 1, dx = d % 3 - 1;
            bool ok = (cy == 0 || (cy == 1 ? dy >= 0 : dy <= 0)) &&
                      (cx == 0 || (cx == 1 ? dx >= 0 : dx <= 0));
            if (ok) s += (j < 50) ? Pp[d * 50 + j] : Bv[d];
        }
        W5c[t] = s;
    }
    __syncthreads();

    // ---- r everywhere via class-weighted 5x5 stencil ----
    {
        int cy = (row == 0) ? 1 : (row == 63) ? 2 : 0;
        #pragma unroll
        for (int p = 0; p < 8; ++p) {
            int xx = cb + p;
            int cx = (xx == 0) ? 1 : (xx == 63) ? 2 : 0;
            const float* Wp = &W5c[(cy * 3 + cx) * 51];
            float acc = Wp[50];
            #pragma unroll
            for (int e = 0; e < 25; ++e) {
                int xi = (row + e / 5) * XROW + (xx + e % 5);
                acc = fmaf(xs0[xi], Wp[e * 2], acc);
                acc = fmaf(xs1[xi], Wp[e * 2 + 1], acc);
            }
            rs[(row + 1) * VROW + (xx + 1)] = acc;
        }
    }
    __syncthreads();

    const int K = VInum[0];

    // ---- Rsw precompute (loop-invariant r-part of w_sw conv) + first step (w_q) ----
    float Rsw[8][10];
    {
        float rwin[3][10];
        #pragma unroll
        for (int i = 0; i < 3; ++i) {
            const float* rp = &rs[(row + i) * VROW + cb];
            #pragma unroll
            for (int j = 0; j < 10; ++j) rwin[i][j] = rp[j];
        }
        float vmax[8];
        #pragma unroll
        for (int a = 0; a < 10; ++a) {
            #pragma unroll
            for (int p = 0; p < 8; ++p) {
                float accR = 0.f, accQ = 0.f;
                #pragma unroll
                for (int d = 0; d < 9; ++d) {
                    float rv = rwin[d / 3][p + d % 3];
                    accR = fmaf(w_sw[d * 20 + a], rv, accR);
                    accQ = fmaf(w_q[d * 20 + a],  rv, accQ);
                }
                Rsw[p][a] = accR;
                vmax[p] = (a == 0) ? accQ : fmaxf(vmax[p], accQ);
            }
        }
        #pragma unroll
        for (int p = 0; p < 8; ++p)
            vpool[0 * VSTR + (row + 1) * VROW + (cb + p + 1)] = vmax[p];
    }
    __syncthreads();

    // ---- K-1 shared-weight VI steps: weights via GLOBAL (s_load/SGPR path) ----
    int cur = 0;
    for (int it = 0; it < K - 1; ++it) {
        const float* vb = &vpool[cur * VSTR + row * VROW + cb];
        float vwin[3][10];
        #pragma unroll
        for (int i = 0; i < 3; ++i)
            #pragma unroll
            for (int j = 0; j < 10; ++j) vwin[i][j] = vb[i * VROW + j];
        int nxt = cur ^ 1;
        float vmax[8];
        #pragma unroll
        for (int a = 0; a < 10; ++a) {
            #pragma unroll
            for (int p = 0; p < 8; ++p) {
                float acc = Rsw[p][a];
                #pragma unroll
                for (int d = 0; d < 9; ++d)
                    acc = fmaf(w_sw[d * 20 + 10 + a], vwin[d / 3][p + d % 3], acc);
                vmax[p] = (a == 0) ? acc : fmaxf(vmax[p], acc);
            }
        }
        #pragma unroll
        for (int p = 0; p < 8; ++p)
            vpool[nxt * VSTR + (row + 1) * VROW + (cb + p + 1)] = vmax[p];
        cur = nxt;
        __syncthreads();
    }

    // ---- final step with w_sw2: q -> global, gather (S1,S2) ----
    const int s1 = S1[b], s2 = S2[b];
    {
        float rwin[3][10], vwin[3][10];
        #pragma unroll
        for (int i = 0; i < 3; ++i) {
            const float* rp = &rs[(row + i) * VROW + cb];
            const float* vb = &vpool[cur * VSTR + (row + i) * VROW + cb];
            #pragma unroll
            for (int j = 0; j < 10; ++j) { rwin[i][j] = rp[j]; vwin[i][j] = vb[j]; }
        }
        float qv[8][10];
        #pragma unroll
        for (int a = 0; a < 10; ++a) {
            #pragma unroll
            for (int p = 0; p < 8; ++p) {
                float acc = 0.f;
                #pragma unroll
                for (int d = 0; d < 9; ++d) {
                    acc = fmaf(w_sw2[d * 20 + a],      rwin[d / 3][p + d % 3], acc);
                    acc = fmaf(w_sw2[d * 20 + 10 + a], vwin[d / 3][p + d % 3], acc);
                }
                qv[p][a] = acc;
            }
        }
        // store q: 80 contiguous floats (8 px x 10 actions), 16B-aligned
        {
            float4* qp4 = (float4*)(out + 2048 + ((size_t)((b * 64 + row) * 64 + cb)) * 10);
            #pragma unroll
            for (int g = 0; g < 20; ++g)
                qp4[g] = make_float4(qv[(g * 4) / 10][(g * 4) % 10],
                                     qv[(g * 4 + 1) / 10][(g * 4 + 1) % 10],
                                     qv[(g * 4 + 2) / 10][(g * 4 + 2) % 10],
                                     qv[(g * 4 + 3) / 10][(g * 4 + 3) % 10]);
        }
        if (row == s1) {
            #pragma unroll
            for (int p = 0; p < 8; ++p)
                if (s2 == cb + p) {
                    #pragma unroll
                    for (int a = 0; a < 10; ++a) qsel[a] = qv[p][a];
                }
        }
    }
    __syncthreads();

    // ---- dense + softmax (thread 0), q_out (threads 0..9) ----
    if (t == 0) {
        float logits[8];
        float m = -1e30f;
        #pragma unroll
        for (int j = 0; j < 8; ++j) {
            float s = 0.f;
            #pragma unroll
            for (int a = 0; a < 10; ++a) s += qsel[a] * w_dense[a * 8 + j];
            logits[j] = s;
            m = fmaxf(m, s);
        }
        float sum = 0.f;
        float e[8];
        #pragma unroll
        for (int j = 0; j < 8; ++j) { e[j] = expf(logits[j] - m); sum += e[j]; }
        float inv = 1.f / sum;
        #pragma unroll
        for (int j = 0; j < 8; ++j) {
            out[b * 8 + j] = logits[j];
            out[1024 + b * 8 + j] = e[j] * inv;
        }
    }
    if (t < 10) out[5244928 + b * 10 + t] = qsel[t];
}

extern "C" void kernel_launch(void* const* d_in, const int* in_sizes, int n_in,
                              void* d_out, int out_size, void* d_ws, size_t ws_size,
                              hipStream_t stream) {
    const float* x      = (const float*)d_in[0];
    const int*   S1     = (const int*)d_in[1];
    const int*   S2     = (const int*)d_in[2];
    const int*   VInum  = (const int*)d_in[3];
    const float* w0     = (const float*)d_in[4];
    const float* b0     = (const float*)d_in[5];
    const float* w_r    = (const float*)d_in[6];
    const float* w_q    = (const float*)d_in[7];
    const float* w_sw   = (const float*)d_in[8];
    const float* w_sw2  = (const float*)d_in[9];
    const float* w_dense= (const float*)d_in[10];
    float* out = (float*)d_out;

    vin_kernel<<<128, 512, 0, stream>>>(x, S1, S2, VInum, w0, b0, w_r, w_q,
                                        w_sw, w_sw2, w_dense, out);
}